// Round 7
// baseline (1000.776 us; speedup 1.0000x reference)
//
#include <hip/hip_runtime.h>

typedef float f32x4 __attribute__((ext_vector_type(4)));
typedef __bf16 bf16x8 __attribute__((ext_vector_type(8)));
typedef unsigned short u16x8 __attribute__((ext_vector_type(8)));
typedef unsigned short u16x4 __attribute__((ext_vector_type(4)));

static __device__ __forceinline__ unsigned short f2bf(float f) {
  unsigned int x = __builtin_bit_cast(unsigned int, f);
  x += 0x7FFFu + ((x >> 16) & 1u);
  return (unsigned short)(x >> 16);
}
static __device__ __forceinline__ float bf2f(unsigned short h) {
  unsigned int x = ((unsigned int)h) << 16;
  return __builtin_bit_cast(float, x);
}

static __device__ __forceinline__ void gload_lds16(const unsigned short* g,
                                                   unsigned short* l) {
  __builtin_amdgcn_global_load_lds(
      (const __attribute__((address_space(1))) void*)g,
      (__attribute__((address_space(3))) void*)l, 16, 0, 0);
}

// ---------------- f32 -> bf16 elementwise (vectorized) ----------------
__global__ __launch_bounds__(256) void k_f32_to_bf16(
    const float* __restrict__ in, unsigned short* __restrict__ out, int n4) {
  int i = blockIdx.x * 256 + threadIdx.x;
  if (i >= n4) return;
  float4 v = reinterpret_cast<const float4*>(in)[i];
  u16x4 o = {f2bf(v.x), f2bf(v.y), f2bf(v.z), f2bf(v.w)};
  reinterpret_cast<u16x4*>(out)[i] = o;
}

// ------- transpose+convert into grouped B^T layout -------
__global__ __launch_bounds__(256) void k_transpose_w(
    const float* __restrict__ in, unsigned short* __restrict__ out, int RG) {
  __shared__ float tile[32][33];
  const int D = 768;
  int z = blockIdx.z;
  int j = z % RG, grp = z / RG;
  const float* A = in + (size_t)z * D * D;
  const size_t ld = (size_t)RG * D;
  unsigned short* O = out + (size_t)grp * D * ld + (size_t)j * D;
  int nt = blockIdx.x * 32, kt = blockIdx.y * 32;
  int tx = threadIdx.x, ty = threadIdx.y;
#pragma unroll
  for (int i = 0; i < 4; ++i)
    tile[ty + i * 8][tx] = A[(size_t)(kt + ty + i * 8) * D + nt + tx];
  __syncthreads();
#pragma unroll
  for (int i = 0; i < 4; ++i)
    O[(size_t)(nt + ty + i * 8) * ld + kt + tx] = f2bf(tile[tx][ty + i * 8]);
}

// ---------------- edge sort by (rel, dst) ----------------
__global__ __launch_bounds__(256) void k_hist(const int* __restrict__ dst,
                                              const int* __restrict__ rel,
                                              int* __restrict__ cnt, int E, int NV) {
  int e = blockIdx.x * 256 + threadIdx.x;
  if (e < E) atomicAdd(&cnt[rel[e] * NV + dst[e]], 1);
}

__global__ __launch_bounds__(256) void k_part(const int* __restrict__ cnt,
                                              int* __restrict__ bsum, int n) {
  __shared__ int wsums[4];
  int blk = blockIdx.x, tid = threadIdx.x;
  int base = blk * 1024 + tid * 4;
  int s = 0;
#pragma unroll
  for (int j = 0; j < 4; ++j) {
    int i = base + j;
    if (i < n) s += cnt[i];
  }
#pragma unroll
  for (int d = 1; d < 64; d <<= 1) s += __shfl_xor(s, d, 64);
  if ((tid & 63) == 0) wsums[tid >> 6] = s;
  __syncthreads();
  if (tid == 0) bsum[blk] = wsums[0] + wsums[1] + wsums[2] + wsums[3];
}

__global__ __launch_bounds__(1024) void k_scan_b(const int* __restrict__ bsum,
                                                 int* __restrict__ bscan, int nb,
                                                 int* __restrict__ off_total) {
  __shared__ int wpre[16];
  int tid = threadIdx.x, lane = tid & 63, w = tid >> 6;
  int v = (tid < nb) ? bsum[tid] : 0;
  int inc = v;
#pragma unroll
  for (int d = 1; d < 64; d <<= 1) {
    int t = __shfl_up(inc, d, 64);
    if (lane >= d) inc += t;
  }
  if (lane == 63) wpre[w] = inc;
  __syncthreads();
  if (w == 0) {
    int vv = (lane < 16) ? wpre[lane] : 0;
    int p = vv;
#pragma unroll
    for (int d = 1; d < 16; d <<= 1) {
      int t = __shfl_up(p, d, 64);
      if (lane >= d) p += t;
    }
    if (lane < 16) wpre[lane] = p - vv;
  }
  __syncthreads();
  if (tid < nb) bscan[tid] = wpre[w] + inc - v;
  if (tid == 1023) *off_total = wpre[15] + inc;
}

__global__ __launch_bounds__(256) void k_scan_f(const int* __restrict__ cnt,
                                                const int* __restrict__ bscan,
                                                int* __restrict__ off, int n) {
  __shared__ int wpre[4];
  int blk = blockIdx.x, tid = threadIdx.x, lane = tid & 63, w = tid >> 6;
  int base = blk * 1024 + tid * 4;
  int v[4];
  int s = 0;
#pragma unroll
  for (int j = 0; j < 4; ++j) {
    int i = base + j;
    v[j] = (i < n) ? cnt[i] : 0;
    s += v[j];
  }
  int inc = s;
#pragma unroll
  for (int d = 1; d < 64; d <<= 1) {
    int t = __shfl_up(inc, d, 64);
    if (lane >= d) inc += t;
  }
  if (lane == 63) wpre[w] = inc;
  __syncthreads();
  int wb = 0;
  for (int j = 0; j < w; ++j) wb += wpre[j];
  int run = bscan[blk] + wb + (inc - s);
#pragma unroll
  for (int j = 0; j < 4; ++j) {
    int i = base + j;
    if (i < n) off[i] = run;
    run += v[j];
  }
}

__global__ __launch_bounds__(256) void k_bucket(
    const int* __restrict__ src, const int* __restrict__ dst,
    const int* __restrict__ rel, const float* __restrict__ norm,
    const int* __restrict__ off, int* __restrict__ fill,
    int* __restrict__ spack, float* __restrict__ snorm, int E, int NV) {
  int e = blockIdx.x * 256 + threadIdx.x;
  if (e >= E) return;
  int key = rel[e] * NV + dst[e];
  int slot = off[key] + atomicAdd(&fill[key], 1);
  spack[slot] = src[e];
  snorm[slot] = norm[e];
}

// ------- gather-aggregate into K-concat A slices -------
__global__ __launch_bounds__(256) void k_gather(
    const unsigned short* __restrict__ h, const int* __restrict__ off,
    const int* __restrict__ spack, const float* __restrict__ snorm,
    unsigned short* __restrict__ Acat, int NV, int r0, int r1, int ld) {
  int v = (blockIdx.x * 256 + threadIdx.x) >> 6;
  int lane = threadIdx.x & 63;
  int col = lane * 4;
  for (int r = r0; r < r1; ++r) {
    float a[12];
#pragma unroll
    for (int j = 0; j < 12; ++j) a[j] = 0.f;
    if (v < NV) {
      int beg = off[r * NV + v], end = off[r * NV + v + 1];
      for (int p = beg; p < end; ++p) {
        const unsigned short* row = h + (size_t)spack[p] * 768 + col;
        float nm = snorm[p];
#pragma unroll
        for (int c = 0; c < 3; ++c) {
          u16x4 vv = *reinterpret_cast<const u16x4*>(row + c * 256);
#pragma unroll
          for (int j = 0; j < 4; ++j) a[c * 4 + j] += nm * bf2f(vv[j]);
        }
      }
    }
    unsigned short* orow = Acat + (size_t)v * ld + (size_t)(r - r0) * 768 + col;
#pragma unroll
    for (int c = 0; c < 3; ++c) {
      u16x4 o = {f2bf(a[c * 4 + 0]), f2bf(a[c * 4 + 1]),
                 f2bf(a[c * 4 + 2]), f2bf(a[c * 4 + 3])};
      *reinterpret_cast<u16x4*>(orow + c * 256) = o;
    }
  }
}

// ---------------- bf16 GEMM: C[M,N] = A[M,K] @ B^T[N,K], f32 accum ----------------
// 256x256 tile, BK=64, 8 waves (wave 128x64). Pipelined 2-phase schedule:
// bv (8 B-frags) prefetched one phase ahead (read at end of B(t), consumed by
// M0(t+1) across the barrier); A-frags streamed in a 2-slot rotation inside
// each MFMA phase (read af[i+1] while MFMAing af[i]). Stage stream:
//   A(t): [T.Ahi, T+1.Alo]   B(t): [T+2.Blo, T+2.Bhi]
// Counted waits: end-A vmcnt(2) (covers T+1.B + T.Ahi, keeps T+1.Alo);
// end-B vmcnt(4) (covers T+1.Alo, keeps T+2.B). 2 barriers/tile.
// 16B-chunk XOR swizzle chunk^=(row&7) on pre-swizzled global source; matching
// XOR on ds_read. A/B rows padded to multiples of 256.
// EPI: 0 = bf16 C; 1 = bf16 relu(acc + C0_f32); 2 = f32 C; 3 = f32 acc + C0.
#define STAGE_A(BUF, HALF, TT)                                                   \
  do {                                                                           \
    const unsigned short* _s =                                                   \
        A + (size_t)(m0 + (HALF) * 128 + srow) * K + (size_t)(TT) * 64 + gcol;   \
    gload_lds16(_s, &As[BUF][HALF][w << 3][0]);                                  \
    gload_lds16(_s + (size_t)64 * K, &As[BUF][HALF][64 + (w << 3)][0]);          \
  } while (0)
#define STAGE_B(BUF, HALF, TT)                                                   \
  do {                                                                           \
    const unsigned short* _s =                                                   \
        B + (size_t)(n0 + (HALF) * 128 + srow) * K + (size_t)(TT) * 64 + gcol;   \
    gload_lds16(_s, &Bs[BUF][HALF][w << 3][0]);                                  \
    gload_lds16(_s + (size_t)64 * K, &Bs[BUF][HALF][64 + (w << 3)][0]);          \
  } while (0)
#define R_BV(BUF)                                                                \
  _Pragma("unroll") for (int nb = 0; nb < 2; ++nb)                               \
  _Pragma("unroll") for (int j = 0; j < 2; ++j)                                  \
  _Pragma("unroll") for (int kk = 0; kk < 2; ++kk)                               \
      bv[nb][j][kk] = *reinterpret_cast<const bf16x8*>(                          \
          &Bs[BUF][nb][wc * 32 + j * 16 + lr][((lg + 4 * kk) ^ (lr & 7)) * 8]);
#define R_AFRAG(SLOT, BUF, HALF, I)                                              \
  _Pragma("unroll") for (int kk = 0; kk < 2; ++kk)                               \
      afs[SLOT][kk] = *reinterpret_cast<const bf16x8*>(                          \
          &As[BUF][HALF][wr * 64 + (I) * 16 + lr][((lg + 4 * kk) ^ (lr & 7)) * 8]);
#define MBLOCK(MA, SLOT, I)                                                      \
  _Pragma("unroll") for (int nb = 0; nb < 2; ++nb)                               \
  _Pragma("unroll") for (int j = 0; j < 2; ++j)                                  \
  _Pragma("unroll") for (int kk = 0; kk < 2; ++kk)                               \
      acc[MA][nb][I][j] = __builtin_amdgcn_mfma_f32_16x16x32_bf16(               \
          afs[SLOT][kk], bv[nb][j][kk], acc[MA][nb][I][j], 0, 0, 0);
#define MPHASE(MA, BUF, HALF)                                                    \
  do {                                                                           \
    R_AFRAG(0, BUF, HALF, 0);                                                    \
    __builtin_amdgcn_s_setprio(1);                                               \
    R_AFRAG(1, BUF, HALF, 1);                                                    \
    MBLOCK(MA, 0, 0);                                                            \
    R_AFRAG(0, BUF, HALF, 2);                                                    \
    MBLOCK(MA, 1, 1);                                                            \
    R_AFRAG(1, BUF, HALF, 3);                                                    \
    MBLOCK(MA, 0, 2);                                                            \
    MBLOCK(MA, 1, 3);                                                            \
    __builtin_amdgcn_s_setprio(0);                                               \
  } while (0)
#define TILE(BUF, T)                                                             \
  do {                                                                           \
    STAGE_A(BUF, 1, T);                          /* T.Ahi */                     \
    if ((T) + 1 < nk) STAGE_A(BUF ^ 1, 0, (T) + 1); /* T+1.Alo */                \
    MPHASE(0, BUF, 0);                           /* M0: stream Alo, uses bv */   \
    if ((T) + 1 < nk)                                                            \
      asm volatile("s_waitcnt vmcnt(2)" ::: "memory");                           \
    else                                                                         \
      asm volatile("s_waitcnt vmcnt(0)" ::: "memory");                           \
    __builtin_amdgcn_s_barrier();                                                \
    asm volatile("" ::: "memory");                                               \
    if ((T) + 2 < nk) {                                                          \
      STAGE_B(BUF, 0, (T) + 2);                  /* T+2.Blo */                   \
      STAGE_B(BUF, 1, (T) + 2);                  /* T+2.Bhi */                   \
    }                                                                            \
    MPHASE(1, BUF, 1);                           /* M1: stream Ahi, reuse bv */  \
    if ((T) + 1 < nk) { R_BV(BUF ^ 1); }         /* bv(t+1), WAR after M1 */     \
    if ((T) + 2 < nk)                                                            \
      asm volatile("s_waitcnt vmcnt(4)" ::: "memory");                           \
    else                                                                         \
      asm volatile("s_waitcnt vmcnt(0)" ::: "memory");                           \
    __builtin_amdgcn_s_barrier();                                                \
    asm volatile("" ::: "memory");                                               \
  } while (0)

template <int EPI>
__global__ __launch_bounds__(512, 2) void k_gemm_tn(
    const unsigned short* __restrict__ A, const unsigned short* __restrict__ B,
    void* __restrict__ Cp, const float* __restrict__ C0,
    int M, int N, int K, int MT, int NT) {
  __shared__ unsigned short As[2][2][128][64];
  __shared__ unsigned short Bs[2][2][128][64];
  const int tid = threadIdx.x;
  const int lane = tid & 63;
  const int w = tid >> 6;
  const int wr = w >> 2;
  const int wc = w & 3;
  const int lr = lane & 15, lg = lane >> 4;

  int bid = blockIdx.x;
  const int per = 8 * NT;
  int grp = bid / per, rem = bid % per;
  int mstart = grp * 8;
  int gsz = MT - mstart; if (gsz > 8) gsz = 8;
  const int mt = mstart + rem % gsz;
  const int ntile = rem / gsz;
  const int m0 = mt * 256, n0 = ntile * 256;

  const int srow = tid >> 3;
  const int gcol = (((tid & 7) ^ (tid >> 3)) & 7) * 8;

  f32x4 acc[2][2][4][2] = {};  // [ma][nb][i][j]
  bf16x8 bv[2][2][2];          // persistent B frags for current tile
  bf16x8 afs[2][2];            // 2-slot A-frag stream
  const int nk = K >> 6;

  // prologue: t0.Alo, t0.Blo, t0.Bhi (cover now); t1.Blo, t1.Bhi (keep 4)
  STAGE_A(0, 0, 0);
  STAGE_B(0, 0, 0);
  STAGE_B(0, 1, 0);
  if (nk > 1) {
    STAGE_B(1, 0, 1);
    STAGE_B(1, 1, 1);
    asm volatile("s_waitcnt vmcnt(4)" ::: "memory");
  } else {
    asm volatile("s_waitcnt vmcnt(0)" ::: "memory");
  }
  __builtin_amdgcn_s_barrier();
  asm volatile("" ::: "memory");
  R_BV(0);  // bv(0)

  for (int t = 0; t < nk; t += 2) {
    TILE(0, t);
    TILE(1, t + 1);
  }

#pragma unroll
  for (int ma = 0; ma < 2; ++ma)
#pragma unroll
    for (int i = 0; i < 4; ++i)
#pragma unroll
      for (int q = 0; q < 4; ++q) {
        int r = m0 + ma * 128 + wr * 64 + i * 16 + lg * 4 + q;
        if (r >= M) continue;
#pragma unroll
        for (int nb = 0; nb < 2; ++nb)
#pragma unroll
          for (int j = 0; j < 2; ++j) {
            int cn = n0 + nb * 128 + wc * 32 + j * 16 + lr;
            float v = acc[ma][nb][i][j][q];
            size_t idx = (size_t)r * N + cn;
            if (EPI == 0) {
              ((unsigned short*)Cp)[idx] = f2bf(v);
            } else if (EPI == 1) {
              v += C0[idx];
              v = v > 0.f ? v : 0.f;
              ((unsigned short*)Cp)[idx] = f2bf(v);
            } else if (EPI == 2) {
              ((float*)Cp)[idx] = v;
            } else {
              ((float*)Cp)[idx] = v + C0[idx];
            }
          }
      }
}

// ---------------- DistMult score ----------------
__global__ __launch_bounds__(256) void k_score(
    const unsigned short* __restrict__ SW, const unsigned short* __restrict__ emb,
    const int* __restrict__ ps, const int* __restrict__ pr, const int* __restrict__ pd,
    const int* __restrict__ ns, const int* __restrict__ nr, const int* __restrict__ nd,
    float* __restrict__ out, int T, int r0, int r1, int ldSW) {
  int t = (blockIdx.x * 256 + threadIdx.x) >> 6;
  if (t >= 2 * T) return;
  int s, r, o;
  if (t < T) { s = ps[t]; r = pr[t]; o = pd[t]; }
  else       { s = ns[t - T]; r = nr[t - T]; o = nd[t - T]; }
  if (r < r0 || r >= r1) return;
  int lane = threadIdx.x & 63;
  int col = lane * 4;
  const unsigned short* a = SW + (size_t)s * ldSW + (size_t)(r - r0) * 768 + col;
  const unsigned short* b = emb + (size_t)o * 768 + col;
  float acc = 0.f;
#pragma unroll
  for (int c = 0; c < 3; ++c) {
    u16x4 va = *reinterpret_cast<const u16x4*>(a + c * 256);
    u16x4 vb = *reinterpret_cast<const u16x4*>(b + c * 256);
#pragma unroll
    for (int j = 0; j < 4; ++j) acc += bf2f(va[j]) * bf2f(vb[j]);
  }
#pragma unroll
  for (int off = 32; off > 0; off >>= 1) acc += __shfl_down(acc, off, 64);
  if (lane == 0) out[t] = acc;
}

extern "C" void kernel_launch(void* const* d_in, const int* in_sizes, int n_in,
                              void* d_out, int out_size, void* d_ws, size_t ws_size,
                              hipStream_t stream) {
  const float* node_feat = (const float*)d_in[0];
  const float* edge_norm = (const float*)d_in[1];
  const float* W_rel = (const float*)d_in[2];
  const float* W_self = (const float*)d_in[3];
  const float* w_relation = (const float*)d_in[4];
  const int* src = (const int*)d_in[5];
  const int* dst = (const int*)d_in[6];
  const int* rel = (const int*)d_in[7];
  const int* pos_src = (const int*)d_in[8];
  const int* pos_rel = (const int*)d_in[9];
  const int* pos_dst = (const int*)d_in[10];
  const int* neg_src = (const int*)d_in[11];
  const int* neg_rel = (const int*)d_in[12];
  const int* neg_dst = (const int*)d_in[13];

  const int D = 768;
  const int NV = in_sizes[0] / D;
  const int E = in_sizes[1];
  const int L = in_sizes[3] / (D * D);
  const int R = in_sizes[4] / (D * D);
  const int T = in_sizes[8];
  const int Mpad = (NV + 255) & ~255;
  const int RN = R * NV;
  const int NB = (RN + 1023) / 1024;

  auto align_up = [](size_t x) { return (x + 255) & ~(size_t)255; };
  size_t sz_wt_rel = align_up((size_t)L * R * D * D * 2);
  size_t sz_wt_self = align_up((size_t)L * D * D * 2);
  size_t sz_wt_score = align_up((size_t)R * D * D * 2);
  size_t sz_h = align_up((size_t)Mpad * D * 2);
  size_t sz_agg = align_up((size_t)Mpad * D * 4);
  size_t sz_cntfill = align_up((size_t)2 * RN * 4);
  size_t sz_off = align_up((size_t)(RN + 8) * 4);
  size_t sz_sp = align_up((size_t)E * 4);
  size_t sz_bs = align_up((size_t)2 * (NB + 8) * 4);
  size_t fixed = sz_wt_rel + sz_wt_self + sz_wt_score + sz_h + sz_agg +
                 sz_cntfill + sz_off + 2 * sz_sp + sz_bs;
  int RG = 4;
  while (RG > 1 && fixed + align_up((size_t)Mpad * RG * D * 2) > ws_size) RG >>= 1;
  const int NGRP = R / RG;

  char* wp = (char*)d_ws;
  unsigned short* wt_rel = (unsigned short*)wp; wp += sz_wt_rel;
  unsigned short* wt_self = (unsigned short*)wp; wp += sz_wt_self;
  unsigned short* wt_score = (unsigned short*)wp; wp += sz_wt_score;
  unsigned short* h = (unsigned short*)wp; wp += sz_h;
  float* agg = (float*)wp; wp += sz_agg;
  int* cnt = (int*)wp; int* fill = cnt + RN; wp += sz_cntfill;
  int* off = (int*)wp; wp += sz_off;
  int* spack = (int*)wp; wp += sz_sp;
  float* snorm = (float*)wp; wp += sz_sp;
  int* bsum = (int*)wp; int* bscan = bsum + NB + 4; wp += sz_bs;
  unsigned short* Acat = (unsigned short*)wp;

  dim3 tb32(32, 8);
  k_f32_to_bf16<<<(NV * D / 4 + 255) / 256, 256, 0, stream>>>(node_feat, h, NV * D / 4);
  if (Mpad > NV)
    hipMemsetAsync(h + (size_t)NV * D, 0, (size_t)(Mpad - NV) * D * 2, stream);
  k_transpose_w<<<dim3(24, 24, L * R), tb32, 0, stream>>>(W_rel, wt_rel, RG);
  k_transpose_w<<<dim3(24, 24, L), tb32, 0, stream>>>(W_self, wt_self, 1);
  k_transpose_w<<<dim3(24, 24, R), tb32, 0, stream>>>(w_relation, wt_score, 1);

  hipMemsetAsync(cnt, 0, (size_t)2 * RN * 4, stream);
  k_hist<<<(E + 255) / 256, 256, 0, stream>>>(dst, rel, cnt, E, NV);
  k_part<<<NB, 256, 0, stream>>>(cnt, bsum, RN);
  k_scan_b<<<1, 1024, 0, stream>>>(bsum, bscan, NB, off + RN);
  k_scan_f<<<NB, 256, 0, stream>>>(cnt, bscan, off, RN);
  k_bucket<<<(E + 255) / 256, 256, 0, stream>>>(src, dst, rel, edge_norm, off, fill,
                                                spack, snorm, E, NV);

  const int MT = Mpad / 256;
  const int KG = RG * D;
  const int gblocks = Mpad / 4;
  for (int l = 0; l < L; ++l) {
    k_gemm_tn<2><<<MT * 3, 512, 0, stream>>>(
        h, wt_self + (size_t)l * D * D, agg, nullptr, NV, D, D, MT, 3);
    for (int gi = 0; gi < NGRP; ++gi) {
      k_gather<<<gblocks, 256, 0, stream>>>(h, off, spack, snorm, Acat, NV,
                                            gi * RG, gi * RG + RG, KG);
      const unsigned short* Bw = wt_rel + (size_t)(l * NGRP + gi) * D * KG;
      if (gi == NGRP - 1)
        k_gemm_tn<1><<<MT * 3, 512, 0, stream>>>(Acat, Bw, h, agg, NV, D, KG, MT, 3);
      else
        k_gemm_tn<3><<<MT * 3, 512, 0, stream>>>(Acat, Bw, agg, agg, NV, D, KG, MT, 3);
    }
  }
  for (int gi = 0; gi < NGRP; ++gi) {
    k_gemm_tn<0><<<MT * RG * 3, 512, 0, stream>>>(
        h, wt_score + (size_t)gi * RG * D * D, Acat, nullptr, NV, KG, D, MT, RG * 3);
    k_score<<<(2 * T + 3) / 4, 256, 0, stream>>>(Acat, h, pos_src, pos_rel, pos_dst,
                                                 neg_src, neg_rel, neg_dst,
                                                 (float*)d_out, T, gi * RG,
                                                 gi * RG + RG, KG);
  }
}

// Round 8
// 936.622 us; speedup vs baseline: 1.0685x; 1.0685x over previous
//
#include <hip/hip_runtime.h>

typedef float f32x4 __attribute__((ext_vector_type(4)));
typedef __bf16 bf16x8 __attribute__((ext_vector_type(8)));
typedef unsigned short u16x8 __attribute__((ext_vector_type(8)));
typedef unsigned short u16x4 __attribute__((ext_vector_type(4)));

static __device__ __forceinline__ unsigned short f2bf(float f) {
  unsigned int x = __builtin_bit_cast(unsigned int, f);
  x += 0x7FFFu + ((x >> 16) & 1u);
  return (unsigned short)(x >> 16);
}
static __device__ __forceinline__ float bf2f(unsigned short h) {
  unsigned int x = ((unsigned int)h) << 16;
  return __builtin_bit_cast(float, x);
}

static __device__ __forceinline__ void gload_lds16(const unsigned short* g,
                                                   unsigned short* l) {
  __builtin_amdgcn_global_load_lds(
      (const __attribute__((address_space(1))) void*)g,
      (__attribute__((address_space(3))) void*)l, 16, 0, 0);
}

// ---------------- f32 -> bf16 elementwise (vectorized) ----------------
__global__ __launch_bounds__(256) void k_f32_to_bf16(
    const float* __restrict__ in, unsigned short* __restrict__ out, int n4) {
  int i = blockIdx.x * 256 + threadIdx.x;
  if (i >= n4) return;
  float4 v = reinterpret_cast<const float4*>(in)[i];
  u16x4 o = {f2bf(v.x), f2bf(v.y), f2bf(v.z), f2bf(v.w)};
  reinterpret_cast<u16x4*>(out)[i] = o;
}

// ------- transpose+convert into grouped B^T layout -------
__global__ __launch_bounds__(256) void k_transpose_w(
    const float* __restrict__ in, unsigned short* __restrict__ out, int RG) {
  __shared__ float tile[32][33];
  const int D = 768;
  int z = blockIdx.z;
  int j = z % RG, grp = z / RG;
  const float* A = in + (size_t)z * D * D;
  const size_t ld = (size_t)RG * D;
  unsigned short* O = out + (size_t)grp * D * ld + (size_t)j * D;
  int nt = blockIdx.x * 32, kt = blockIdx.y * 32;
  int tx = threadIdx.x, ty = threadIdx.y;
#pragma unroll
  for (int i = 0; i < 4; ++i)
    tile[ty + i * 8][tx] = A[(size_t)(kt + ty + i * 8) * D + nt + tx];
  __syncthreads();
#pragma unroll
  for (int i = 0; i < 4; ++i)
    O[(size_t)(nt + ty + i * 8) * ld + kt + tx] = f2bf(tile[tx][ty + i * 8]);
}

// ---------------- edge sort by (rel, dst) ----------------
__global__ __launch_bounds__(256) void k_hist(const int* __restrict__ dst,
                                              const int* __restrict__ rel,
                                              int* __restrict__ cnt, int E, int NV) {
  int e = blockIdx.x * 256 + threadIdx.x;
  if (e < E) atomicAdd(&cnt[rel[e] * NV + dst[e]], 1);
}

__global__ __launch_bounds__(256) void k_part(const int* __restrict__ cnt,
                                              int* __restrict__ bsum, int n) {
  __shared__ int wsums[4];
  int blk = blockIdx.x, tid = threadIdx.x;
  int base = blk * 1024 + tid * 4;
  int s = 0;
#pragma unroll
  for (int j = 0; j < 4; ++j) {
    int i = base + j;
    if (i < n) s += cnt[i];
  }
#pragma unroll
  for (int d = 1; d < 64; d <<= 1) s += __shfl_xor(s, d, 64);
  if ((tid & 63) == 0) wsums[tid >> 6] = s;
  __syncthreads();
  if (tid == 0) bsum[blk] = wsums[0] + wsums[1] + wsums[2] + wsums[3];
}

__global__ __launch_bounds__(1024) void k_scan_b(const int* __restrict__ bsum,
                                                 int* __restrict__ bscan, int nb,
                                                 int* __restrict__ off_total) {
  __shared__ int wpre[16];
  int tid = threadIdx.x, lane = tid & 63, w = tid >> 6;
  int v = (tid < nb) ? bsum[tid] : 0;
  int inc = v;
#pragma unroll
  for (int d = 1; d < 64; d <<= 1) {
    int t = __shfl_up(inc, d, 64);
    if (lane >= d) inc += t;
  }
  if (lane == 63) wpre[w] = inc;
  __syncthreads();
  if (w == 0) {
    int vv = (lane < 16) ? wpre[lane] : 0;
    int p = vv;
#pragma unroll
    for (int d = 1; d < 16; d <<= 1) {
      int t = __shfl_up(p, d, 64);
      if (lane >= d) p += t;
    }
    if (lane < 16) wpre[lane] = p - vv;
  }
  __syncthreads();
  if (tid < nb) bscan[tid] = wpre[w] + inc - v;
  if (tid == 1023) *off_total = wpre[15] + inc;
}

__global__ __launch_bounds__(256) void k_scan_f(const int* __restrict__ cnt,
                                                const int* __restrict__ bscan,
                                                int* __restrict__ off, int n) {
  __shared__ int wpre[4];
  int blk = blockIdx.x, tid = threadIdx.x, lane = tid & 63, w = tid >> 6;
  int base = blk * 1024 + tid * 4;
  int v[4];
  int s = 0;
#pragma unroll
  for (int j = 0; j < 4; ++j) {
    int i = base + j;
    v[j] = (i < n) ? cnt[i] : 0;
    s += v[j];
  }
  int inc = s;
#pragma unroll
  for (int d = 1; d < 64; d <<= 1) {
    int t = __shfl_up(inc, d, 64);
    if (lane >= d) inc += t;
  }
  if (lane == 63) wpre[w] = inc;
  __syncthreads();
  int wb = 0;
  for (int j = 0; j < w; ++j) wb += wpre[j];
  int run = bscan[blk] + wb + (inc - s);
#pragma unroll
  for (int j = 0; j < 4; ++j) {
    int i = base + j;
    if (i < n) off[i] = run;
    run += v[j];
  }
}

__global__ __launch_bounds__(256) void k_bucket(
    const int* __restrict__ src, const int* __restrict__ dst,
    const int* __restrict__ rel, const float* __restrict__ norm,
    const int* __restrict__ off, int* __restrict__ fill,
    int* __restrict__ spack, float* __restrict__ snorm, int E, int NV) {
  int e = blockIdx.x * 256 + threadIdx.x;
  if (e >= E) return;
  int key = rel[e] * NV + dst[e];
  int slot = off[key] + atomicAdd(&fill[key], 1);
  spack[slot] = src[e];
  snorm[slot] = norm[e];
}

// ------- gather-aggregate into K-concat A slices -------
__global__ __launch_bounds__(256) void k_gather(
    const unsigned short* __restrict__ h, const int* __restrict__ off,
    const int* __restrict__ spack, const float* __restrict__ snorm,
    unsigned short* __restrict__ Acat, int NV, int r0, int r1, int ld) {
  int v = (blockIdx.x * 256 + threadIdx.x) >> 6;
  int lane = threadIdx.x & 63;
  int col = lane * 4;
  for (int r = r0; r < r1; ++r) {
    float a[12];
#pragma unroll
    for (int j = 0; j < 12; ++j) a[j] = 0.f;
    if (v < NV) {
      int beg = off[r * NV + v], end = off[r * NV + v + 1];
      for (int p = beg; p < end; ++p) {
        const unsigned short* row = h + (size_t)spack[p] * 768 + col;
        float nm = snorm[p];
#pragma unroll
        for (int c = 0; c < 3; ++c) {
          u16x4 vv = *reinterpret_cast<const u16x4*>(row + c * 256);
#pragma unroll
          for (int j = 0; j < 4; ++j) a[c * 4 + j] += nm * bf2f(vv[j]);
        }
      }
    }
    unsigned short* orow = Acat + (size_t)v * ld + (size_t)(r - r0) * 768 + col;
#pragma unroll
    for (int c = 0; c < 3; ++c) {
      u16x4 o = {f2bf(a[c * 4 + 0]), f2bf(a[c * 4 + 1]),
                 f2bf(a[c * 4 + 2]), f2bf(a[c * 4 + 3])};
      *reinterpret_cast<u16x4*>(orow + c * 256) = o;
    }
  }
}

// ================= shared GEMM pieces (256x256 tile, BK=64, 8 waves) =========
// 16B-chunk XOR swizzle chunk^=(row&7) on pre-swizzled global source; matching
// XOR on ds_read. A/B rows padded to multiples of 256.
// EPI: 0 = bf16 C; 1 = bf16 relu(acc + C0_f32); 2 = f32 C; 3 = f32 acc + C0.
#define STAGE_A(BUF, HALF, TT)                                                   \
  do {                                                                           \
    const unsigned short* _s =                                                   \
        A + (size_t)(m0 + (HALF) * 128 + srow) * K + (size_t)(TT) * 64 + gcol;   \
    gload_lds16(_s, &As[BUF][HALF][w << 3][0]);                                  \
    gload_lds16(_s + (size_t)64 * K, &As[BUF][HALF][64 + (w << 3)][0]);          \
  } while (0)
#define STAGE_B(BUF, HALF, TT)                                                   \
  do {                                                                           \
    const unsigned short* _s =                                                   \
        B + (size_t)(n0 + (HALF) * 128 + srow) * K + (size_t)(TT) * 64 + gcol;   \
    gload_lds16(_s, &Bs[BUF][HALF][w << 3][0]);                                  \
    gload_lds16(_s + (size_t)64 * K, &Bs[BUF][HALF][64 + (w << 3)][0]);          \
  } while (0)
#define GEMM_PRE()                                                               \
  const int tid = threadIdx.x;                                                   \
  const int lane = tid & 63;                                                     \
  const int w = tid >> 6;                                                        \
  const int wr = w >> 2;                                                         \
  const int wc = w & 3;                                                          \
  const int lr = lane & 15, lg = lane >> 4;                                      \
  int bid = blockIdx.x;                                                          \
  const int per = 8 * NT;                                                        \
  int grp = bid / per, rem = bid % per;                                          \
  int mstart = grp * 8;                                                          \
  int gsz = MT - mstart;                                                         \
  if (gsz > 8) gsz = 8;                                                          \
  const int mt = mstart + rem % gsz;                                             \
  const int ntile = rem / gsz;                                                   \
  const int m0 = mt * 256, n0 = ntile * 256;                                     \
  const int srow = tid >> 3;                                                     \
  const int gcol = (((tid & 7) ^ (tid >> 3)) & 7) * 8;                           \
  const int nk = K >> 6;
#define GEMM_EPILOGUE()                                                          \
  _Pragma("unroll") for (int ma = 0; ma < 2; ++ma)                               \
  _Pragma("unroll") for (int i = 0; i < 4; ++i)                                  \
  _Pragma("unroll") for (int q = 0; q < 4; ++q) {                                \
    int r = m0 + ma * 128 + wr * 64 + i * 16 + lg * 4 + q;                       \
    if (r >= M) continue;                                                        \
    _Pragma("unroll") for (int nb = 0; nb < 2; ++nb)                             \
    _Pragma("unroll") for (int j = 0; j < 2; ++j) {                              \
      int cn = n0 + nb * 128 + wc * 32 + j * 16 + lr;                            \
      float v = acc[ma][nb][i][j][q];                                            \
      size_t idx = (size_t)r * N + cn;                                           \
      if (EPI == 0) {                                                            \
        ((unsigned short*)Cp)[idx] = f2bf(v);                                    \
      } else if (EPI == 1) {                                                     \
        v += C0[idx];                                                            \
        v = v > 0.f ? v : 0.f;                                                   \
        ((unsigned short*)Cp)[idx] = f2bf(v);                                    \
      } else if (EPI == 2) {                                                     \
        ((float*)Cp)[idx] = v;                                                   \
      } else {                                                                   \
        ((float*)Cp)[idx] = v + C0[idx];                                         \
      }                                                                          \
    }                                                                            \
  }

// ---------------- k_gemm_tn: round-6 2-phase schedule (control) ----------------
#define R_BV6(BUF)                                                               \
  _Pragma("unroll") for (int nb = 0; nb < 2; ++nb)                               \
  _Pragma("unroll") for (int j = 0; j < 2; ++j)                                  \
  _Pragma("unroll") for (int kk = 0; kk < 2; ++kk)                               \
      bv[nb][j][kk] = *reinterpret_cast<const bf16x8*>(                          \
          &Bs[BUF][nb][wc * 32 + j * 16 + lr][((lg + 4 * kk) ^ (lr & 7)) * 8]);
#define R_AF6(BUF, HALF)                                                         \
  _Pragma("unroll") for (int i = 0; i < 4; ++i)                                  \
  _Pragma("unroll") for (int kk = 0; kk < 2; ++kk)                               \
      af[i][kk] = *reinterpret_cast<const bf16x8*>(                              \
          &As[BUF][HALF][wr * 64 + i * 16 + lr][((lg + 4 * kk) ^ (lr & 7)) * 8]);

template <int EPI>
__global__ __launch_bounds__(512, 2) void k_gemm_tn(
    const unsigned short* __restrict__ A, const unsigned short* __restrict__ B,
    void* __restrict__ Cp, const float* __restrict__ C0,
    int M, int N, int K, int MT, int NT) {
  __shared__ unsigned short As[2][2][128][64];
  __shared__ unsigned short Bs[2][2][128][64];
  GEMM_PRE();
  f32x4 acc[2][2][4][2] = {};

  STAGE_A(0, 0, 0);
  STAGE_B(0, 1, 0);
  STAGE_A(0, 1, 0);
  STAGE_B(0, 0, 0);
  if (nk > 1) {
    STAGE_A(1, 0, 1);
    STAGE_B(1, 1, 1);
  }

  bf16x8 af[4][2], bv[2][2][2];
  for (int t = 0; t < nk; ++t) {
    const int buf = t & 1;
    if (t + 1 < nk)
      asm volatile("s_waitcnt vmcnt(4)" ::: "memory");
    else
      asm volatile("s_waitcnt vmcnt(0)" ::: "memory");
    __builtin_amdgcn_s_barrier();
    asm volatile("" ::: "memory");
    // ---- Phase A: ma = 0 ----
    R_AF6(buf, 0);
    R_BV6(buf);
    if (t + 1 < nk) {
      STAGE_A(buf ^ 1, 1, t + 1);
      STAGE_B(buf ^ 1, 0, t + 1);
    }
    __builtin_amdgcn_s_setprio(1);
#pragma unroll
    for (int i = 0; i < 4; ++i)
#pragma unroll
      for (int nb = 0; nb < 2; ++nb)
#pragma unroll
        for (int j = 0; j < 2; ++j)
#pragma unroll
          for (int kk = 0; kk < 2; ++kk)
            acc[0][nb][i][j] = __builtin_amdgcn_mfma_f32_16x16x32_bf16(
                af[i][kk], bv[nb][j][kk], acc[0][nb][i][j], 0, 0, 0);
    __builtin_amdgcn_s_setprio(0);
    asm volatile("" ::: "memory");
    __builtin_amdgcn_s_barrier();
    asm volatile("" ::: "memory");
    // ---- Phase B: ma = 1, reuse bv ----
    R_AF6(buf, 1);
    if (t + 2 < nk) {
      STAGE_A(buf, 0, t + 2);
      STAGE_B(buf, 1, t + 2);
    }
    __builtin_amdgcn_s_setprio(1);
#pragma unroll
    for (int i = 0; i < 4; ++i)
#pragma unroll
      for (int nb = 0; nb < 2; ++nb)
#pragma unroll
        for (int j = 0; j < 2; ++j)
#pragma unroll
          for (int kk = 0; kk < 2; ++kk)
            acc[1][nb][i][j] = __builtin_amdgcn_mfma_f32_16x16x32_bf16(
                af[i][kk], bv[nb][j][kk], acc[1][nb][i][j], 0, 0, 0);
    __builtin_amdgcn_s_setprio(0);
  }
  GEMM_EPILOGUE();
}

// ---------------- k_gemm8: faithful 8-phase (4 phases/tile) template ----------
// Per phase: {ds_reads for this quadrant} {stage 1 half-tile} [ph4: vmcnt]
//            barrier; lgkmcnt(0); sched_barrier; setprio(1); 16 MFMA; setprio(0); barrier
// Quadrant order (0,0)->(0,1)->(1,1)->(1,0); bv0/bv1/af register-held (24 reads/tile).
// Stage stream: ph1: t+1.Ahi, ph2: t+2.Alo, ph3: t+2.Blo, ph4: t+2.Bhi.
// vmcnt(6) at ph4 (3 half-tiles in flight) retires all of tile t+1 incl. its
// Ahi (staged at t.ph1, 8th-newest); tail uses vmcnt(0). Accounting verified.
#define R_BV8(DST, BUF, HALF)                                                    \
  _Pragma("unroll") for (int j = 0; j < 2; ++j)                                  \
  _Pragma("unroll") for (int kk = 0; kk < 2; ++kk)                               \
      DST[j][kk] = *reinterpret_cast<const bf16x8*>(                             \
          &Bs[BUF][HALF][wc * 32 + j * 16 + lr][((lg + 4 * kk) ^ (lr & 7)) * 8]);
#define MB16(MA, NB, BV)                                                         \
  __builtin_amdgcn_s_setprio(1);                                                 \
  _Pragma("unroll") for (int i = 0; i < 4; ++i)                                  \
  _Pragma("unroll") for (int j = 0; j < 2; ++j)                                  \
  _Pragma("unroll") for (int kk = 0; kk < 2; ++kk)                               \
      acc[MA][NB][i][j] = __builtin_amdgcn_mfma_f32_16x16x32_bf16(               \
          af[i][kk], BV[j][kk], acc[MA][NB][i][j], 0, 0, 0);                     \
  __builtin_amdgcn_s_setprio(0);
#define MIDSYNC                                                                  \
  asm volatile("" ::: "memory");                                                 \
  __builtin_amdgcn_s_barrier();                                                  \
  asm volatile("s_waitcnt lgkmcnt(0)" ::: "memory");                             \
  __builtin_amdgcn_sched_barrier(0);
#define ENDBAR                                                                   \
  asm volatile("" ::: "memory");                                                 \
  __builtin_amdgcn_s_barrier();                                                  \
  asm volatile("" ::: "memory");

template <int EPI>
__global__ __launch_bounds__(512, 2) void k_gemm8(
    const unsigned short* __restrict__ A, const unsigned short* __restrict__ B,
    void* __restrict__ Cp, const float* __restrict__ C0,
    int M, int N, int K, int MT, int NT) {
  __shared__ unsigned short As[2][2][128][64];
  __shared__ unsigned short Bs[2][2][128][64];
  GEMM_PRE();
  f32x4 acc[2][2][4][2] = {};
  bf16x8 af[4][2], bv0[2][2], bv1[2][2];

  // prologue: t0 {Alo,Blo,Bhi,Ahi}; t1 {Alo,Blo,Bhi}  (t1.Ahi comes at t0.ph1)
  STAGE_A(0, 0, 0);
  STAGE_B(0, 0, 0);
  STAGE_B(0, 1, 0);
  STAGE_A(0, 1, 0);
  if (nk > 1) {
    STAGE_A(1, 0, 1);
    STAGE_B(1, 0, 1);
    STAGE_B(1, 1, 1);
    asm volatile("s_waitcnt vmcnt(6)" ::: "memory");
  } else {
    asm volatile("s_waitcnt vmcnt(0)" ::: "memory");
  }
  __builtin_amdgcn_s_barrier();
  asm volatile("" ::: "memory");

  for (int t = 0; t < nk; ++t) {
    const int b = t & 1;
    // ---- ph1: quadrant (0,0) ----
    R_AF6(b, 0);
    R_BV8(bv0, b, 0);
    if (t + 1 < nk) STAGE_A(b ^ 1, 1, t + 1);  // t+1.Ahi
    MIDSYNC;
    MB16(0, 0, bv0);
    ENDBAR;
    // ---- ph2: quadrant (0,1), reuse af ----
    R_BV8(bv1, b, 1);
    if (t + 2 < nk) STAGE_A(b, 0, t + 2);      // t+2.Alo
    MIDSYNC;
    MB16(0, 1, bv1);
    ENDBAR;
    // ---- ph3: quadrant (1,1), reuse bv1 ----
    R_AF6(b, 1);
    if (t + 2 < nk) STAGE_B(b, 0, t + 2);      // t+2.Blo
    MIDSYNC;
    MB16(1, 1, bv1);
    ENDBAR;
    // ---- ph4: quadrant (1,0), reuse af + bv0; counted vmcnt once/tile ----
    if (t + 2 < nk) {
      STAGE_B(b, 1, t + 2);                    // t+2.Bhi
      asm volatile("s_waitcnt vmcnt(6)" ::: "memory");
    } else {
      asm volatile("s_waitcnt vmcnt(0)" ::: "memory");
    }
    MIDSYNC;
    MB16(1, 0, bv0);
    ENDBAR;
  }
  GEMM_EPILOGUE();
}

// ---------------- DistMult score ----------------
__global__ __launch_bounds__(256) void k_score(
    const unsigned short* __restrict__ SW, const unsigned short* __restrict__ emb,
    const int* __restrict__ ps, const int* __restrict__ pr, const int* __restrict__ pd,
    const int* __restrict__ ns, const int* __restrict__ nr, const int* __restrict__ nd,
    float* __restrict__ out, int T, int r0, int r1, int ldSW) {
  int t = (blockIdx.x * 256 + threadIdx.x) >> 6;
  if (t >= 2 * T) return;
  int s, r, o;
  if (t < T) { s = ps[t]; r = pr[t]; o = pd[t]; }
  else       { s = ns[t - T]; r = nr[t - T]; o = nd[t - T]; }
  if (r < r0 || r >= r1) return;
  int lane = threadIdx.x & 63;
  int col = lane * 4;
  const unsigned short* a = SW + (size_t)s * ldSW + (size_t)(r - r0) * 768 + col;
  const unsigned short* b = emb + (size_t)o * 768 + col;
  float acc = 0.f;
#pragma unroll
  for (int c = 0; c < 3; ++c) {
    u16x4 va = *reinterpret_cast<const u16x4*>(a + c * 256);
    u16x4 vb = *reinterpret_cast<const u16x4*>(b + c * 256);
#pragma unroll
    for (int j = 0; j < 4; ++j) acc += bf2f(va[j]) * bf2f(vb[j]);
  }
#pragma unroll
  for (int off = 32; off > 0; off >>= 1) acc += __shfl_down(acc, off, 64);
  if (lane == 0) out[t] = acc;
}

extern "C" void kernel_launch(void* const* d_in, const int* in_sizes, int n_in,
                              void* d_out, int out_size, void* d_ws, size_t ws_size,
                              hipStream_t stream) {
  const float* node_feat = (const float*)d_in[0];
  const float* edge_norm = (const float*)d_in[1];
  const float* W_rel = (const float*)d_in[2];
  const float* W_self = (const float*)d_in[3];
  const float* w_relation = (const float*)d_in[4];
  const int* src = (const int*)d_in[5];
  const int* dst = (const int*)d_in[6];
  const int* rel = (const int*)d_in[7];
  const int* pos_src = (const int*)d_in[8];
  const int* pos_rel = (const int*)d_in[9];
  const int* pos_dst = (const int*)d_in[10];
  const int* neg_src = (const int*)d_in[11];
  const int* neg_rel = (const int*)d_in[12];
  const int* neg_dst = (const int*)d_in[13];

  const int D = 768;
  const int NV = in_sizes[0] / D;
  const int E = in_sizes[1];
  const int L = in_sizes[3] / (D * D);
  const int R = in_sizes[4] / (D * D);
  const int T = in_sizes[8];
  const int Mpad = (NV + 255) & ~255;
  const int RN = R * NV;
  const int NB = (RN + 1023) / 1024;

  auto align_up = [](size_t x) { return (x + 255) & ~(size_t)255; };
  size_t sz_wt_rel = align_up((size_t)L * R * D * D * 2);
  size_t sz_wt_self = align_up((size_t)L * D * D * 2);
  size_t sz_wt_score = align_up((size_t)R * D * D * 2);
  size_t sz_h = align_up((size_t)Mpad * D * 2);
  size_t sz_agg = align_up((size_t)Mpad * D * 4);
  size_t sz_cntfill = align_up((size_t)2 * RN * 4);
  size_t sz_off = align_up((size_t)(RN + 8) * 4);
  size_t sz_sp = align_up((size_t)E * 4);
  size_t sz_bs = align_up((size_t)2 * (NB + 8) * 4);
  size_t fixed = sz_wt_rel + sz_wt_self + sz_wt_score + sz_h + sz_agg +
                 sz_cntfill + sz_off + 2 * sz_sp + sz_bs;
  int RG = 4;
  while (RG > 1 && fixed + align_up((size_t)Mpad * RG * D * 2) > ws_size) RG >>= 1;
  const int NGRP = R / RG;

  char* wp = (char*)d_ws;
  unsigned short* wt_rel = (unsigned short*)wp; wp += sz_wt_rel;
  unsigned short* wt_self = (unsigned short*)wp; wp += sz_wt_self;
  unsigned short* wt_score = (unsigned short*)wp; wp += sz_wt_score;
  unsigned short* h = (unsigned short*)wp; wp += sz_h;
  float* agg = (float*)wp; wp += sz_agg;
  int* cnt = (int*)wp; int* fill = cnt + RN; wp += sz_cntfill;
  int* off = (int*)wp; wp += sz_off;
  int* spack = (int*)wp; wp += sz_sp;
  float* snorm = (float*)wp; wp += sz_sp;
  int* bsum = (int*)wp; int* bscan = bsum + NB + 4; wp += sz_bs;
  unsigned short* Acat = (unsigned short*)wp;

  dim3 tb32(32, 8);
  k_f32_to_bf16<<<(NV * D / 4 + 255) / 256, 256, 0, stream>>>(node_feat, h, NV * D / 4);
  if (Mpad > NV)
    hipMemsetAsync(h + (size_t)NV * D, 0, (size_t)(Mpad - NV) * D * 2, stream);
  k_transpose_w<<<dim3(24, 24, L * R), tb32, 0, stream>>>(W_rel, wt_rel, RG);
  k_transpose_w<<<dim3(24, 24, L), tb32, 0, stream>>>(W_self, wt_self, 1);
  k_transpose_w<<<dim3(24, 24, R), tb32, 0, stream>>>(w_relation, wt_score, 1);

  hipMemsetAsync(cnt, 0, (size_t)2 * RN * 4, stream);
  k_hist<<<(E + 255) / 256, 256, 0, stream>>>(dst, rel, cnt, E, NV);
  k_part<<<NB, 256, 0, stream>>>(cnt, bsum, RN);
  k_scan_b<<<1, 1024, 0, stream>>>(bsum, bscan, NB, off + RN);
  k_scan_f<<<NB, 256, 0, stream>>>(cnt, bscan, off, RN);
  k_bucket<<<(E + 255) / 256, 256, 0, stream>>>(src, dst, rel, edge_norm, off, fill,
                                                spack, snorm, E, NV);

  const int MT = Mpad / 256;
  const int KG = RG * D;
  const int gblocks = Mpad / 4;
  for (int l = 0; l < L; ++l) {
    k_gemm8<2><<<MT * 3, 512, 0, stream>>>(
        h, wt_self + (size_t)l * D * D, agg, nullptr, NV, D, D, MT, 3);
    for (int gi = 0; gi < NGRP; ++gi) {
      k_gather<<<gblocks, 256, 0, stream>>>(h, off, spack, snorm, Acat, NV,
                                            gi * RG, gi * RG + RG, KG);
      const unsigned short* Bw = wt_rel + (size_t)(l * NGRP + gi) * D * KG;
      if (gi == NGRP - 1)
        k_gemm8<1><<<MT * 3, 512, 0, stream>>>(Acat, Bw, h, agg, NV, D, KG, MT, 3);
      else
        k_gemm8<3><<<MT * 3, 512, 0, stream>>>(Acat, Bw, agg, agg, NV, D, KG, MT, 3);
    }
  }
  // scoring GEMMs: round-6 2-phase kernel as within-probe A/B control
  for (int gi = 0; gi < NGRP; ++gi) {
    k_gemm_tn<0><<<MT * RG * 3, 512, 0, stream>>>(
        h, wt_score + (size_t)gi * RG * D * D, Acat, nullptr, NV, KG, D, MT, RG * 3);
    k_score<<<(2 * T + 3) / 4, 256, 0, stream>>>(Acat, h, pos_src, pos_rel, pos_dst,
                                                 neg_src, neg_rel, neg_dst,
                                                 (float*)d_out, T, gi * RG,
                                                 gi * RG + RG, KG);
  }
}